// Round 9
// baseline (426.212 us; speedup 1.0000x reference)
//
#include <hip/hip_runtime.h>

// Problem constants
#define B_   256
#define T_   500
#define DIN  700
#define H_   200
#define NO   400      // H*BR
#define DOUT 35
#define NKC  22       // K chunks of 32

typedef _Float16 half_t;
typedef __attribute__((ext_vector_type(8))) _Float16 half8;
typedef __attribute__((ext_vector_type(4))) float floatx4;

#define SX 16.0f      // exact pow2 scale for x
#define SW 4096.0f    // exact pow2 scale for W
#define INV_S (1.0f / 65536.0f)

__device__ __forceinline__ float sigmoidf_(float x) {
    return 1.0f / (1.0f + expf(-x));
}

__device__ __forceinline__ void gload_lds16(const float* g, float* l) {
    __builtin_amdgcn_global_load_lds(
        (const __attribute__((address_space(1))) unsigned int*)g,
        (__attribute__((address_space(3))) unsigned int*)l,
        16, 0, 0);
}

// ---------------------------------------------------------------------------
// Pre-pass: W -> (hi,lo) fp16 in MFMA-fragment order.
// t = ((kc*25 + nfg)*64 + lane); lane = la + 16*lb.
// value j = W[nfg*16+la][kc*32 + lb*8 + j] (0 beyond col 700), scaled by SW.
__global__ __launch_bounds__(256) void cvt_wfrag(
    const float* __restrict__ W, half_t* __restrict__ Whf, half_t* __restrict__ Wlf)
{
    int t = blockIdx.x * 256 + threadIdx.x;
    if (t >= NKC * 25 * 64) return;
    int lane = t & 63;
    int rest = t >> 6;
    int nfg  = rest % 25;
    int kc   = rest / 25;
    int la = lane & 15, lb = lane >> 4;
    int row = nfg * 16 + la;
    int col = kc * 32 + lb * 8;
    half8 hh, ll;
    #pragma unroll
    for (int j = 0; j < 8; ++j) {
        float v = (col + j < DIN) ? W[(size_t)row * DIN + col + j] : 0.0f;
        float s = v * SW;
        half_t h = (half_t)s;
        hh[j] = h;
        ll[j] = (half_t)(s - (float)h);
    }
    *reinterpret_cast<half8*>(&Whf[(size_t)t * 8]) = hh;
    *reinterpret_cast<half8*>(&Wlf[(size_t)t * 8]) = ll;
}

// ---------------------------------------------------------------------------
// Split-fp16 MFMA GEMM, 32x80 wave tile, 3-deep counted-vmcnt pipeline.
// A: global_load_lds into wave-private LDS (3 buffers, both-sides swizzle,
//    zero barriers). B: fragment-packed, 3 named register buffers.
// Straight-line main loop (no branches) -> compiler keeps counted waits.
__global__ __launch_bounds__(256, 2) void dh_gemm_3d(
    const float* __restrict__ x,
    const half_t* __restrict__ Whf, const half_t* __restrict__ Wlf,
    const float* __restrict__ bin, float* __restrict__ Y)
{
    __shared__ float Abuf[4][3][1024];   // 4 waves x 3 bufs x (32 rows x 32 f) = 48KB

    // XCD-bijective swizzle: nwg=5000 = 8*625 exactly
    int p = blockIdx.x;
    int L = (p & 7) * 625 + (p >> 3);
    int by = L / 5, bx = L - by * 5;

    const int w    = threadIdx.x >> 6;
    const int lane = threadIdx.x & 63;
    const int la   = lane & 15;
    const int lb   = lane >> 4;

    const int m0 = by * 128 + w * 32;    // this wave's 32 M rows
    const int o0 = bx * 80;

    floatx4 acc[2][5];
    #pragma unroll
    for (int mf = 0; mf < 2; ++mf)
        #pragma unroll
        for (int nf = 0; nf < 5; ++nf) {
            floatx4 z = {0.f, 0.f, 0.f, 0.f};
            acc[mf][nf] = z;
        }

    // ---- staging addresses (per-lane global src, pre-swizzled; linear LDS dest)
    const int srow = lane >> 3;              // 0..7 (row within 8-row slab)
    const int sseg = (lane & 7) ^ srow;      // swizzled global 16B-seg
    const float* a0 = x + (size_t)(m0 +  0 + srow) * DIN + sseg * 4;
    const float* a1 = x + (size_t)(m0 +  8 + srow) * DIN + sseg * 4;
    const float* a2 = x + (size_t)(m0 + 16 + srow) * DIN + sseg * 4;
    const float* a3 = x + (size_t)(m0 + 24 + srow) * DIN + sseg * 4;

    // ---- B pointers (fragment-packed; advance 12800 halves per chunk)
    const half_t* pWh = Whf + ((size_t)(bx * 5) * 64 + lane) * 8;
    const half_t* pWl = Wlf + ((size_t)(bx * 5) * 64 + lane) * 8;

    // ---- ds_read offsets (floats), reader-side swizzle q^(la&7)
    const int o00 = (la) * 32      + (((lb * 2)     ^ (la & 7)) << 2);
    const int o01 = (la) * 32      + (((lb * 2 + 1) ^ (la & 7)) << 2);
    const int o10 = (16 + la) * 32 + (((lb * 2)     ^ (la & 7)) << 2);
    const int o11 = (16 + la) * 32 + (((lb * 2 + 1) ^ (la & 7)) << 2);

    half8 B0h[5], B0l[5], B1h[5], B1l[5], B2h[5], B2l[5];
    half8 ah[2], al[2];
    float4 f00, f01, f10, f11;

#define STAGE(r) do {                                                   \
        float* d = &Abuf[w][r][0];                                      \
        gload_lds16(a0, d);                                             \
        gload_lds16(a1, d + 256);                                       \
        gload_lds16(a2, d + 512);                                       \
        gload_lds16(a3, d + 768);                                       \
        a0 += 32; a1 += 32; a2 += 32; a3 += 32;                         \
    } while (0)

#define LOADB(RH, RL) do {                                              \
        _Pragma("unroll")                                               \
        for (int nf = 0; nf < 5; ++nf) {                                \
            RH[nf] = *reinterpret_cast<const half8*>(pWh + nf * 512);   \
            RL[nf] = *reinterpret_cast<const half8*>(pWl + nf * 512);   \
        }                                                               \
        pWh += 12800; pWl += 12800;                                     \
    } while (0)

#define DSR(r) do {                                                     \
        const float* bse = &Abuf[w][r][0];                              \
        f00 = *reinterpret_cast<const float4*>(bse + o00);              \
        f01 = *reinterpret_cast<const float4*>(bse + o01);              \
        f10 = *reinterpret_cast<const float4*>(bse + o10);              \
        f11 = *reinterpret_cast<const float4*>(bse + o11);              \
    } while (0)

#define CONV() do {                                                     \
        _Pragma("unroll")                                               \
        for (int mf = 0; mf < 2; ++mf) {                                \
            float vv[8];                                                \
            *reinterpret_cast<float4*>(&vv[0]) = mf ? f10 : f00;        \
            *reinterpret_cast<float4*>(&vv[4]) = mf ? f11 : f01;        \
            half8 hh, ll;                                               \
            _Pragma("unroll")                                           \
            for (int j = 0; j < 8; ++j) {                               \
                float s = vv[j] * SX;                                   \
                half_t h = (half_t)s;                                   \
                hh[j] = h;                                              \
                ll[j] = (half_t)(s - (float)h);                         \
            }                                                           \
            ah[mf] = hh; al[mf] = ll;                                   \
        }                                                               \
    } while (0)

#define MFMAS(RH, RL) do {                                              \
        _Pragma("unroll")                                               \
        for (int mf = 0; mf < 2; ++mf)                                  \
            _Pragma("unroll")                                           \
            for (int nf = 0; nf < 5; ++nf)                              \
                acc[mf][nf] = __builtin_amdgcn_mfma_f32_16x16x32_f16(ah[mf], RH[nf], acc[mf][nf], 0, 0, 0); \
        _Pragma("unroll")                                               \
        for (int mf = 0; mf < 2; ++mf)                                  \
            _Pragma("unroll")                                           \
            for (int nf = 0; nf < 5; ++nf)                              \
                acc[mf][nf] = __builtin_amdgcn_mfma_f32_16x16x32_f16(ah[mf], RL[nf], acc[mf][nf], 0, 0, 0); \
        _Pragma("unroll")                                               \
        for (int mf = 0; mf < 2; ++mf)                                  \
            _Pragma("unroll")                                           \
            for (int nf = 0; nf < 5; ++nf)                              \
                acc[mf][nf] = __builtin_amdgcn_mfma_f32_16x16x32_f16(al[mf], RH[nf], acc[mf][nf], 0, 0, 0); \
    } while (0)

#define WAITVM(N) asm volatile("s_waitcnt vmcnt(" #N ")" ::: "memory"); __builtin_amdgcn_sched_barrier(0)
#define WAITLG()  asm volatile("s_waitcnt lgkmcnt(0)" ::: "memory"); __builtin_amdgcn_sched_barrier(0)
#define SBAR()    __builtin_amdgcn_sched_barrier(0)

    // main body: consume chunk kc from buf r (r = kc%3), stage/load kc+3
#define BODY(r)  do {                                                   \
        WAITVM(38);            /* A-stage(kc) landed (3-deep) */        \
        DSR(r);                                                         \
        WAITLG();              /* ds data in regs before overwrite */   \
        STAGE(r); SBAR();      /* stage kc+3 into freed buffer */       \
        CONV();                                                         \
        WAITVM(32);            /* B(kc) landed */                       \
        __builtin_amdgcn_s_setprio(1);                                  \
        MFMAS(B##r##h, B##r##l);                                        \
        __builtin_amdgcn_s_setprio(0); SBAR();                          \
        LOADB(B##r##h, B##r##l);   /* B(kc+3) after consume */          \
    } while (0)

    // ---- prologue: S(0) B(0) S(1) B(1) S(2) B(2)  (42 vmem in flight)
    STAGE(0); SBAR();
    LOADB(B0h, B0l); SBAR();
    STAGE(1); SBAR();
    LOADB(B1h, B1l); SBAR();
    STAGE(2); SBAR();
    LOADB(B2h, B2l); SBAR();

    // ---- main loop: kc = 0..17, stages/loads 3..20. Branch-free bodies.
    #pragma unroll 1
    for (int I = 0; I < 6; ++I) {
        BODY(0);
        BODY(1);
        BODY(2);
    }

    // ---- body kc=18 (r=0): stage chunk 21 CLAMPED (cols 700..703 -> 696)
    {
        WAITVM(38);
        DSR(0);
        WAITLG();
        {
            int colf = 21 * 32 + sseg * 4;
            colf = (colf > 696) ? 696 : colf;   // per-lane clamp; B zero at k>=700
            const float* c0 = x + (size_t)(m0 +  0 + srow) * DIN + colf;
            const float* c1 = x + (size_t)(m0 +  8 + srow) * DIN + colf;
            const float* c2 = x + (size_t)(m0 + 16 + srow) * DIN + colf;
            const float* c3 = x + (size_t)(m0 + 24 + srow) * DIN + colf;
            float* d = &Abuf[w][0][0];
            gload_lds16(c0, d);
            gload_lds16(c1, d + 256);
            gload_lds16(c2, d + 512);
            gload_lds16(c3, d + 768);
        }
        SBAR();
        CONV();
        WAITVM(32);
        __builtin_amdgcn_s_setprio(1);
        MFMAS(B0h, B0l);
        __builtin_amdgcn_s_setprio(0); SBAR();
        LOADB(B0h, B0l);               // B(21)
    }
    // ---- drain bodies kc=19,20,21 (no stage/load; exact decreasing counts)
    {
        WAITVM(38); DSR(1); WAITLG(); CONV();
        WAITVM(28);
        __builtin_amdgcn_s_setprio(1); MFMAS(B1h, B1l); __builtin_amdgcn_s_setprio(0); SBAR();
    }
    {
        WAITVM(24); DSR(2); WAITLG(); CONV();
        WAITVM(14);
        __builtin_amdgcn_s_setprio(1); MFMAS(B2h, B2l); __builtin_amdgcn_s_setprio(0); SBAR();
    }
    {
        WAITVM(10); DSR(0); WAITLG(); CONV();
        WAITVM(0);
        __builtin_amdgcn_s_setprio(1); MFMAS(B0h, B0l); __builtin_amdgcn_s_setprio(0); SBAR();
    }

    // ---- epilogue: C/D layout col = lane&15, row = (lane>>4)*4 + reg
    float bo[5];
    #pragma unroll
    for (int nf = 0; nf < 5; ++nf) bo[nf] = bin[o0 + nf * 16 + la];

    #pragma unroll
    for (int mf = 0; mf < 2; ++mf) {
        int mbase = m0 + mf * 16 + lb * 4;
        #pragma unroll
        for (int rg = 0; rg < 4; ++rg) {
            int mm = mbase + rg;
            int bb = mm / T_;
            int tt = mm - bb * T_;
            float* yrow = &Y[((size_t)tt * B_ + bb) * NO + o0 + la];
            #pragma unroll
            for (int nf = 0; nf < 5; ++nf)
                yrow[nf * 16] = acc[mf][nf][rg] * INV_S + bo[nf];
        }
    }
#undef STAGE
#undef LOADB
#undef DSR
#undef CONV
#undef MFMAS
#undef WAITVM
#undef WAITLG
#undef SBAR
#undef BODY
}

// ---------------------------------------------------------------------------
// Fallback fp32 GEMM (known-good) if workspace too small.
#define BM 256
#define BN 64
#define BK 16
__global__ __launch_bounds__(256) void dh_gemm_in(
    const float* __restrict__ x, const float* __restrict__ Wt,
    const float* __restrict__ bin, float* __restrict__ Y)
{
    __shared__ float As[BK][BM + 4];
    __shared__ float Bs[BK][BN + 4];
    const int tid = threadIdx.x;
    const int tx = tid & 7;
    const int ty = tid >> 3;
    const int m0 = blockIdx.y * BM;
    const int o0 = blockIdx.x * BN;

    float acc[8][8];
    #pragma unroll
    for (int r = 0; r < 8; ++r)
        #pragma unroll
        for (int c = 0; c < 8; ++c) acc[r][c] = 0.0f;

    const int srow = tid >> 2;
    const int skq  = (tid & 3) << 2;

    for (int k0 = 0; k0 < DIN; k0 += BK) {
        float4 areg[4];
        #pragma unroll
        for (int i = 0; i < 4; ++i) {
            int idx = tid + i * 256;
            int row = idx >> 2;
            int kq  = (idx & 3) << 2;
            int kg  = k0 + kq;
            if (kg < DIN)
                areg[i] = *reinterpret_cast<const float4*>(&x[(size_t)(m0 + row) * DIN + kg]);
            else
                areg[i] = make_float4(0.f, 0.f, 0.f, 0.f);
        }
        float4 breg;
        {
            int kg = k0 + skq;
            int o  = o0 + srow;
            if (kg < DIN && o < NO)
                breg = *reinterpret_cast<const float4*>(&Wt[(size_t)o * DIN + kg]);
            else
                breg = make_float4(0.f, 0.f, 0.f, 0.f);
        }
        __syncthreads();
        #pragma unroll
        for (int i = 0; i < 4; ++i) {
            int idx = tid + i * 256;
            int row = idx >> 2;
            int kq  = (idx & 3) << 2;
            As[kq + 0][row] = areg[i].x;
            As[kq + 1][row] = areg[i].y;
            As[kq + 2][row] = areg[i].z;
            As[kq + 3][row] = areg[i].w;
        }
        Bs[skq + 0][srow] = breg.x;
        Bs[skq + 1][srow] = breg.y;
        Bs[skq + 2][srow] = breg.z;
        Bs[skq + 3][srow] = breg.w;
        __syncthreads();

        #pragma unroll
        for (int k = 0; k < BK; ++k) {
            float a[8], bb[8];
            *reinterpret_cast<float4*>(&a[0])  = *reinterpret_cast<const float4*>(&As[k][ty * 8]);
            *reinterpret_cast<float4*>(&a[4])  = *reinterpret_cast<const float4*>(&As[k][ty * 8 + 4]);
            *reinterpret_cast<float4*>(&bb[0]) = *reinterpret_cast<const float4*>(&Bs[k][tx * 8]);
            *reinterpret_cast<float4*>(&bb[4]) = *reinterpret_cast<const float4*>(&Bs[k][tx * 8 + 4]);
            #pragma unroll
            for (int r = 0; r < 8; ++r)
                #pragma unroll
                for (int c = 0; c < 8; ++c)
                    acc[r][c] = fmaf(a[r], bb[c], acc[r][c]);
        }
    }

    float bo[8];
    #pragma unroll
    for (int c = 0; c < 8; ++c) {
        int o = o0 + tx * 8 + c;
        bo[c] = (o < NO) ? bin[o] : 0.0f;
    }
    const int ob = o0 + tx * 8;
    if (ob < NO) {
        #pragma unroll
        for (int r = 0; r < 8; ++r) {
            int m = m0 + ty * 8 + r;
            int b = m / T_;
            int t = m - b * T_;
            float* yrow = &Y[((size_t)t * B_ + b) * NO];
            float4 v0 = make_float4(acc[r][0] + bo[0], acc[r][1] + bo[1],
                                    acc[r][2] + bo[2], acc[r][3] + bo[3]);
            float4 v1 = make_float4(acc[r][4] + bo[4], acc[r][5] + bo[5],
                                    acc[r][6] + bo[6], acc[r][7] + bo[7]);
            *reinterpret_cast<float4*>(&yrow[ob])     = v0;
            *reinterpret_cast<float4*>(&yrow[ob + 4]) = v1;
        }
    }
}

// ---------------------------------------------------------------------------
// Phase 2: sequential LIF scan over T per (b,h) neuron.
__global__ __launch_bounds__(64) void dh_scan(
    const float* __restrict__ Y, const float* __restrict__ tau_n,
    const float* __restrict__ tau_m, float* __restrict__ counts)
{
    int g = blockIdx.x * 64 + threadIdx.x;   // b*H + h
    int b = g / H_;
    int h = g - b * H_;
    (void)b;
    float beta0 = sigmoidf_(tau_n[h * 2 + 0]);
    float beta1 = sigmoidf_(tau_n[h * 2 + 1]);
    float alpha = sigmoidf_(tau_m[h]);
    float omb0 = 1.0f - beta0, omb1 = 1.0f - beta1, oma = 1.0f - alpha;
    const float2* Yp = reinterpret_cast<const float2*>(Y);

    float v = 0.f, i0 = 0.f, i1 = 0.f, cnt = 0.f;
    #pragma unroll 1
    for (int t0 = 0; t0 < T_; t0 += 10) {
        float2 yb[10];
        #pragma unroll
        for (int j = 0; j < 10; ++j)
            yb[j] = Yp[(size_t)(t0 + j) * (B_ * H_) + g];
        #pragma unroll
        for (int j = 0; j < 10; ++j) {
            i0 = beta0 * i0 + omb0 * yb[j].x;
            i1 = beta1 * i1 + omb1 * yb[j].y;
            float it = i0 + i1;
            v = alpha * v + oma * it;
            if (v >= 1.0f) { v -= 1.0f; cnt += 1.0f; }
        }
    }
    counts[g] = cnt;
}

// Phase 3: out[b][o] = sum_h counts[b][h] * W_out[o][h] + b_out[o]
__global__ __launch_bounds__(64) void dh_out(
    const float* __restrict__ counts, const float* __restrict__ W_out,
    const float* __restrict__ b_out, float* __restrict__ out)
{
    int b = blockIdx.x;
    int o = threadIdx.x;
    if (o >= DOUT) return;
    float acc = b_out[o];
    const float* c = &counts[(size_t)b * H_];
    const float* w = &W_out[(size_t)o * H_];
    #pragma unroll 4
    for (int h = 0; h < H_; ++h)
        acc = fmaf(c[h], w[h], acc);
    out[(size_t)b * DOUT + o] = acc;
}

extern "C" void kernel_launch(void* const* d_in, const int* in_sizes, int n_in,
                              void* d_out, int out_size, void* d_ws, size_t ws_size,
                              hipStream_t stream) {
    const float* x     = (const float*)d_in[0];  // (B,T,DIN)
    const float* W_in  = (const float*)d_in[1];  // (NO,DIN)
    const float* b_in  = (const float*)d_in[2];  // (NO)
    const float* tau_n = (const float*)d_in[3];  // (H,BR)
    const float* tau_m = (const float*)d_in[4];  // (H)
    const float* W_out = (const float*)d_in[5];  // (DOUT,H)
    const float* b_out = (const float*)d_in[6];  // (DOUT)
    float* out = (float*)d_out;                  // (B,DOUT)

    float* Y      = (float*)d_ws;                         // 51.2M floats
    float* counts = Y + (size_t)T_ * B_ * NO;             // 51200 floats

    const size_t nfrag_halves = (size_t)NKC * 25 * 64 * 8;   // 281600
    size_t need = ((size_t)T_ * B_ * NO + (size_t)B_ * H_) * 4
                + 2 * nfrag_halves * 2;

    if (ws_size >= need) {
        half_t* Whf = (half_t*)(counts + (size_t)B_ * H_);
        half_t* Wlf = Whf + nfrag_halves;

        cvt_wfrag<<<(NKC * 25 * 64 + 255) / 256, 256, 0, stream>>>(W_in, Whf, Wlf);
        dh_gemm_3d<<<5000, 256, 0, stream>>>(x, Whf, Wlf, b_in, Y);
    } else {
        dim3 g1(7, 500);
        dh_gemm_in<<<g1, 256, 0, stream>>>(x, W_in, b_in, Y);
    }

    dh_scan<<<(B_ * H_) / 64, 64, 0, stream>>>(Y, tau_n, tau_m, counts);
    dh_out<<<B_, 64, 0, stream>>>(counts, W_out, b_out, out);
}